// Round 12
// baseline (115.209 us; speedup 1.0000x reference)
//
#include <hip/hip_runtime.h>
#include <stdint.h>

// Segmented top-4 over CSR (N=500K segments, E=32M edges).
// d_out = f32: [N*4 topk_vals][N*4 topk_idx-as-float], 16 MB.
// Pads MUST be bf16-finite (checker compares in bf16; -inf pad => nan).
//
// v7 = v6 main kernel + DEGREE BINNING: a counting-sort prologue groups
// segments by k = ceil(deg/32) so the 8 segments sharing a wave need the
// same number of scan iterations -> the max-of-groups loop waste (~2.2x)
// disappears. ws layout: [64 u32 cnt][64 u32 cur][nseg i32 perm].

#define NB 64   // buckets: k = min(ceil(deg/32), 63)

template <int CTRL>
__device__ __forceinline__ float dppf(float x) {
  int r = __builtin_amdgcn_update_dpp(__float_as_int(x), __float_as_int(x),
                                      CTRL, 0xF, 0xF, false);
  return __int_as_float(r);
}
template <int CTRL>
__device__ __forceinline__ int dppi(int x) {
  return __builtin_amdgcn_update_dpp(x, x, CTRL, 0xF, 0xF, false);
}

// 8-lane reductions: quad_perm xor1 (0xB1), xor2 (0x4E), row_half_mirror
// (0x141) — all stay inside the 8-lane group.
__device__ __forceinline__ float grpmax8(float x) {
  x = fmaxf(x, dppf<0xB1>(x));
  x = fmaxf(x, dppf<0x4E>(x));
  x = fmaxf(x, dppf<0x141>(x));
  return x;
}
__device__ __forceinline__ int grpmin8(int x) {
  x = min(x, dppi<0xB1>(x));
  x = min(x, dppi<0x4E>(x));
  x = min(x, dppi<0x141>(x));
  return x;
}

// ---------------- binning prologue --------------------------------------
__global__ void zero_k(uint32_t* cnt) {          // 1 block, 128 threads
  cnt[threadIdx.x] = 0;                          // covers cnt[64] + cur[64]
}

__global__ __launch_bounds__(256) void hist_k(const int* __restrict__ rp,
                                              int nseg, uint32_t* cnt) {
  __shared__ uint32_t h[NB];
  const int tid = threadIdx.x;
  if (tid < NB) h[tid] = 0;
  __syncthreads();
  const int i = blockIdx.x * 256 + tid;
  if (i < nseg) {
    const int deg = rp[i + 1] - rp[i];
    const int k = min((deg + 31) >> 5, NB - 1);
    atomicAdd(&h[k], 1u);
  }
  __syncthreads();
  if (tid < NB && h[tid]) atomicAdd(&cnt[tid], h[tid]);
}

__global__ void prefix_k(uint32_t* cnt, uint32_t* cur) {   // 1 block
  if (threadIdx.x == 0) {
    uint32_t s = 0;
    for (int k = 0; k < NB; ++k) {
      const uint32_t c = cnt[k];
      cnt[k] = s; cur[k] = s; s += c;
    }
  }
}

__global__ __launch_bounds__(256) void scat_k(const int* __restrict__ rp,
                                              int nseg, uint32_t* cur,
                                              int* __restrict__ perm) {
  __shared__ uint32_t h[NB], base[NB];
  const int tid = threadIdx.x;
  if (tid < NB) h[tid] = 0;
  __syncthreads();
  const int i = blockIdx.x * 256 + tid;
  int k = 0; uint32_t r = 0;
  if (i < nseg) {
    const int deg = rp[i + 1] - rp[i];
    k = min((deg + 31) >> 5, NB - 1);
    r = atomicAdd(&h[k], 1u);                    // rank within block
  }
  __syncthreads();
  if (tid < NB && h[tid]) base[tid] = atomicAdd(&cur[tid], h[tid]);
  __syncthreads();
  if (i < nseg) perm[base[k] + r] = i;
}

// ---------------- main kernel (v6 scan/merge, perm indirection) ----------
__global__ __launch_bounds__(256) void seg_top4_v7(
    const int* __restrict__ rp,
    const float* __restrict__ esc,
    float4* __restrict__ out_v,
    float4* __restrict__ out_i,
    const int* __restrict__ perm,    // may be nullptr (identity)
    int nseg, int E)
{
  const int lane = threadIdx.x & 63;
  const int g    = lane >> 3;          // group (segment slot) within wave: 0..7
  const int t    = lane & 7;           // lane within 8-lane group
  const int w    = (int)((blockIdx.x * (unsigned)blockDim.x + threadIdx.x) >> 6);
  const int pos  = (w << 3) + g;
  const int posc = min(pos, nseg - 1);
  const int seg  = perm ? perm[posc] : posc;

  const int lo  = rp[seg];
  const int hi  = rp[seg + 1];
  const int deg = hi - lo;             // group-uniform

  const float NEG = __int_as_float(0xFF800000u);   // -inf sentinel
  float av0 = NEG, av1 = NEG, av2 = NEG, av3 = NEG;
  int   ai0 = -1,  ai1 = -1,  ai2 = -1,  ai3 = -1;

  // med3 sorted-quad insert: values 4 inst, indices via masks on OLD vals.
#define INS4(V, EIDX) do {                                       \
    const float _v = (V); const int _e = (EIDX);                 \
    const bool c0 = _v > av0;                                    \
    const bool c1 = _v > av1;                                    \
    const bool c2 = _v > av2;                                    \
    const bool c3 = _v > av3;                                    \
    const int n0 = c0 ? _e  : ai0;                               \
    const int n1 = c0 ? ai0 : (c1 ? _e : ai1);                   \
    const int n2 = c1 ? ai1 : (c2 ? _e : ai2);                   \
    const int n3 = c2 ? ai2 : (c3 ? _e : ai3);                   \
    const float m1 = __builtin_amdgcn_fmed3f(_v, av0, av1);      \
    const float m2 = __builtin_amdgcn_fmed3f(_v, av1, av2);      \
    const float m3 = __builtin_amdgcn_fmed3f(_v, av2, av3);      \
    av0 = fmaxf(av0, _v);                                        \
    av1 = m1; av2 = m2; av3 = m3;                                \
    ai0 = n0; ai1 = n1; ai2 = n2; ai3 = n3;                      \
  } while (0)

#define PROC(F, QS, REL) do {                                            \
    const float v0 = ((unsigned)((REL) + 0) < (unsigned)deg) ? (F).x : NEG; \
    const float v1 = ((unsigned)((REL) + 1) < (unsigned)deg) ? (F).y : NEG; \
    const float v2 = ((unsigned)((REL) + 2) < (unsigned)deg) ? (F).z : NEG; \
    const float v3 = ((unsigned)((REL) + 3) < (unsigned)deg) ? (F).w : NEG; \
    INS4(v0, (QS) + 0);                                                  \
    INS4(v1, (QS) + 1);                                                  \
    INS4(v2, (QS) + 2);                                                  \
    INS4(v3, (QS) + 3);                                                  \
  } while (0)

  // ---- scan: depth-2 pipelined aligned float4, 32 elems/group-iter -------
  const int Ec = E - 4;                // 4-aligned (E % 4 == 0)
  int qs  = (lo & ~3) + (t << 2);      // 4-aligned quad start for this lane
  int rel = qs - lo;                   // offset within segment (may be <0)

  float4 f  = *reinterpret_cast<const float4*>(esc + min(qs, Ec));
  float4 fn = *reinterpret_cast<const float4*>(esc + min(qs + 32, Ec));

  while (__any(qs < hi)) {
    const float4 fnn =
        *reinterpret_cast<const float4*>(esc + min(qs + 64, Ec));
    PROC(f, qs, rel);
    f = fn; fn = fnn;
    qs  += 32;
    rel += 32;
  }
#undef PROC
#undef INS4

  // ---- merge: 4 rounds of 8-lane DPP extract-max, min-idx tie-break ------
  float rv0, rv1, rv2, rv3;
  int   ri0, ri1, ri2, ri3;
  #pragma unroll
  for (int r = 0; r < 4; ++r) {
    const float M = grpmax8(av0);
    const int   c = (av0 == M) ? ai0 : 0x7FFFFFFF;
    const int   W = grpmin8(c);              // stable: min original idx wins
    if (r == 0)      { rv0 = M; ri0 = W; }
    else if (r == 1) { rv1 = M; ri1 = W; }
    else if (r == 2) { rv2 = M; ri2 = W; }
    else             { rv3 = M; ri3 = W; }
    if (r < 3) {
      const bool p = (c == W);   // exactly the winning lane(s); unique idx
      av0 = p ? av1 : av0; ai0 = p ? ai1 : ai0;
      av1 = p ? av2 : av1; ai1 = p ? ai2 : ai1;
      av2 = p ? av3 : av2; ai2 = p ? ai3 : ai2;
    }
  }

  // ---- epilogue: lane 0 of each group writes two float4 ------------------
  if (t == 0 && pos < nseg) {
    float4 vv, ii;
    vv.x = (0 < deg) ? rv0 : -1.0e38f;  ii.x = (0 < deg) ? (float)ri0 : -1.0f;
    vv.y = (1 < deg) ? rv1 : -1.0e38f;  ii.y = (1 < deg) ? (float)ri1 : -1.0f;
    vv.z = (2 < deg) ? rv2 : -1.0e38f;  ii.z = (2 < deg) ? (float)ri2 : -1.0f;
    vv.w = (3 < deg) ? rv3 : -1.0e38f;  ii.w = (3 < deg) ? (float)ri3 : -1.0f;
    out_v[seg] = vv;     // pads stay bf16-finite: -1.0e38f -> bf16 0xFF16
    out_i[seg] = ii;
  }
}

extern "C" void kernel_launch(void* const* d_in, const int* in_sizes, int n_in,
                              void* d_out, int out_size, void* d_ws, size_t ws_size,
                              hipStream_t stream) {
  const int*   rp  = (const int*)d_in[0];    // row_ptr [N+1]
  const float* esc = (const float*)d_in[1];  // edge_scores [E]
  const int   nseg = in_sizes[0] - 1;
  const int   E    = in_sizes[1];

  float4* out_v = (float4*)d_out;                                  // vals [N]
  float4* out_i = (float4*)((float*)d_out + (size_t)nseg * 4);     // idx  [N]

  const int segs_per_block = 32;   // 256 threads = 4 waves = 32 segments
  const int grid = (nseg + segs_per_block - 1) / segs_per_block;
  const int nblk = (nseg + 255) / 256;

  const size_t need = (size_t)(2 * NB + nseg) * 4;
  if (ws_size >= need) {
    uint32_t* cnt  = (uint32_t*)d_ws;
    uint32_t* cur  = cnt + NB;
    int*      perm = (int*)(cnt + 2 * NB);
    zero_k<<<1, 2 * NB, 0, stream>>>(cnt);
    hist_k<<<nblk, 256, 0, stream>>>(rp, nseg, cnt);
    prefix_k<<<1, 64, 0, stream>>>(cnt, cur);
    scat_k<<<nblk, 256, 0, stream>>>(rp, nseg, cur, perm);
    seg_top4_v7<<<grid, 256, 0, stream>>>(rp, esc, out_v, out_i, perm, nseg, E);
  } else {
    seg_top4_v7<<<grid, 256, 0, stream>>>(rp, esc, out_v, out_i, nullptr, nseg, E);
  }
}